// Round 4
// baseline (1356.780 us; speedup 1.0000x reference)
//
#include <hip/hip_runtime.h>
#include <stdint.h>
#include <stddef.h>

using u16 = unsigned short;

__device__ __forceinline__ float u2f(u16 u) {
  union { unsigned i; float f; } c; c.i = ((unsigned)u) << 16; return c.f;
}
__device__ __forceinline__ u16 f2u(float f) {
  union { float f; unsigned i; } c; c.f = f;
  unsigned u = c.i;
  u += 0x7fffu + ((u >> 16) & 1u);   // RNE to bf16
  return (u16)(u >> 16);
}
__device__ __forceinline__ float sigm(float x) { return 1.f / (1.f + expf(-x)); }

typedef __attribute__((ext_vector_type(8))) short bfrag;   // 8 bf16 = 4 VGPRs
typedef __attribute__((ext_vector_type(4))) float f32x4;

// ---- dtype detection: fp32 N(0,1) words land in [1e-6,1e4]; bf16 pairs
// reinterpreted as fp32 land at ~1e33..Inf or ~1e-38.
__global__ void detect_kernel(const float* __restrict__ x, int* __restrict__ flag) {
  __shared__ int cnt;
  if (threadIdx.x == 0) cnt = 0;
  __syncthreads();
  int local = 0;
  for (int i = threadIdx.x; i < 8192; i += 256) {
    float v = x[i];
    float a = fabsf(v);
    if (a > 1e-6f && a < 1e4f) local++;    // NaN/Inf/denorm/huge all fail
  }
  atomicAdd(&cnt, local);
  __syncthreads();
  if (threadIdx.x == 0) *flag = (cnt > 6144) ? 1 : 0;   // 1 = inputs are fp32
}

// convert (or copy) a tensor to bf16 in ws
__global__ void cvt_kernel(const void* __restrict__ src, u16* __restrict__ dst,
                           int n, const int* __restrict__ flag) {
  int i = blockIdx.x * 256 + threadIdx.x;
  if (i >= n) return;
  if (*flag) dst[i] = f2u(((const float*)src)[i]);
  else       dst[i] = ((const u16*)src)[i];
}

// C = epilogue(A @ W^T). A:[rows,K] (bf16, or runtime fp32 if ADYN), row-major lda.
// W:[cols,K] bf16 row-major ldw. rows%128==0, cols%128==0, K%64==0.
// MODE 0: outb = bf16(relu(acc + ubuf[(b*64+w)*512 + col]))   (ubuf holds bm already)
// MODE 1: outb = bf16(relu(acc + bias[col]))
// MODE 2: atomicAdd(pred[row], sum_col relu(acc + bias[col]) * wlo[col])
// MODE 3: outf = acc + bias[col]
// MODE 4: outb = bf16(relu(sigm(pred[row]) * acc + bias[col]))
template <int MODE, bool ADYN>
__global__ __launch_bounds__(256)
void gemm_bt(const void* __restrict__ Av, int lda, size_t abase,
             const u16* __restrict__ W, int ldw, int K,
             const u16* __restrict__ bias,
             const float* __restrict__ ubuf,
             const u16* __restrict__ wlo,
             float* __restrict__ pred,
             u16* __restrict__ outb,
             float* __restrict__ outf,
             int ldc,
             const int* __restrict__ aflag)
{
  __shared__ u16 As[128 * 64];
  __shared__ u16 Bs[128 * 64];
  const int tid  = threadIdx.x;
  const int wave = tid >> 6, lane = tid & 63;
  const int wr = wave >> 1, wc = wave & 1;
  const int quad = lane >> 4, l16 = lane & 15;
  const int row0 = blockIdx.y * 128;
  const int col0 = blockIdx.x * 128;
  bool a32 = false;
  if (ADYN) a32 = (*aflag != 0);

  f32x4 acc[4][4];
#pragma unroll
  for (int i = 0; i < 4; i++)
#pragma unroll
    for (int j = 0; j < 4; j++)
#pragma unroll
      for (int r = 0; r < 4; r++) acc[i][j][r] = 0.f;

  for (int k0 = 0; k0 < K; k0 += 64) {
    uint4 ra[4], rb[4];
#pragma unroll
    for (int i = 0; i < 4; i++) {
      const int idx  = i * 256 + tid;        // 1024 16B-chunks per tile
      const int srow = idx >> 3;             // 0..127
      const int scol = (idx & 7) * 8;        // 0..56, elems
      const size_t aoff = (abase + (size_t)(row0 + srow)) * lda + k0 + scol;
      if (ADYN && a32) {
        const float* p = (const float*)Av + aoff;
        float4 f0 = *(const float4*)(p);
        float4 f1 = *(const float4*)(p + 4);
        ra[i].x = (unsigned)f2u(f0.x) | ((unsigned)f2u(f0.y) << 16);
        ra[i].y = (unsigned)f2u(f0.z) | ((unsigned)f2u(f0.w) << 16);
        ra[i].z = (unsigned)f2u(f1.x) | ((unsigned)f2u(f1.y) << 16);
        ra[i].w = (unsigned)f2u(f1.z) | ((unsigned)f2u(f1.w) << 16);
      } else {
        ra[i] = *(const uint4*)((const u16*)Av + aoff);
      }
      rb[i] = *(const uint4*)(W + (size_t)(col0 + srow) * ldw + k0 + scol);
    }
    __syncthreads();                         // prior tile's LDS reads complete
#pragma unroll
    for (int i = 0; i < 4; i++) {
      const int idx  = i * 256 + tid;
      const int srow = idx >> 3;
      const int scol = (idx & 7) * 8;
      *(uint4*)(As + srow * 64 + scol) = ra[i];
      *(uint4*)(Bs + srow * 64 + scol) = rb[i];
    }
    __syncthreads();
#pragma unroll
    for (int kk = 0; kk < 64; kk += 32) {
      bfrag af[4], bfr[4];
#pragma unroll
      for (int mt = 0; mt < 4; mt++)
        af[mt] = *(const bfrag*)(As + (wr * 64 + mt * 16 + l16) * 64 + kk + quad * 8);
#pragma unroll
      for (int nt = 0; nt < 4; nt++)
        bfr[nt] = *(const bfrag*)(Bs + (wc * 64 + nt * 16 + l16) * 64 + kk + quad * 8);
#pragma unroll
      for (int mt = 0; mt < 4; mt++)
#pragma unroll
        for (int nt = 0; nt < 4; nt++)
          acc[mt][nt] = __builtin_amdgcn_mfma_f32_16x16x32_bf16(af[mt], bfr[nt], acc[mt][nt], 0, 0, 0);
    }
  }

  // C/D layout (verified m89/m91): col = lane&15, row = quad*4 + reg
#pragma unroll
  for (int mt = 0; mt < 4; mt++) {
    if (MODE == 2) {
#pragma unroll
      for (int r = 0; r < 4; r++) {
        const int rg = row0 + wr * 64 + mt * 16 + quad * 4 + r;
        float s = 0.f;
#pragma unroll
        for (int nt = 0; nt < 4; nt++) {
          const int cg = col0 + wc * 64 + nt * 16 + l16;
          float v = acc[mt][nt][r] + u2f(bias[cg]);
          v = fmaxf(v, 0.f);
          s += v * u2f(wlo[cg]);
        }
#pragma unroll
        for (int off = 1; off < 16; off <<= 1) s += __shfl_xor(s, off, 16);
        if (l16 == 0) atomicAdd(pred + rg, s);
      }
    } else {
#pragma unroll
      for (int nt = 0; nt < 4; nt++) {
#pragma unroll
        for (int r = 0; r < 4; r++) {
          const int rg = row0 + wr * 64 + mt * 16 + quad * 4 + r;
          const int cg = col0 + wc * 64 + nt * 16 + l16;
          float v = acc[mt][nt][r];
          if (MODE == 0) {
            const int urow = ((rg >> 12) << 6) | (rg & 63);   // b*64 + w
            v += ubuf[(size_t)urow * 512 + cg];
            v = fmaxf(v, 0.f);
            outb[(size_t)rg * ldc + cg] = f2u(v);
          } else if (MODE == 1) {
            v += u2f(bias[cg]);
            v = fmaxf(v, 0.f);
            outb[(size_t)rg * ldc + cg] = f2u(v);
          } else if (MODE == 4) {
            const float sg = sigm(pred[rg]);
            v = sg * v + u2f(bias[cg]);
            v = fmaxf(v, 0.f);
            outb[(size_t)rg * ldc + cg] = f2u(v);
          } else {  // MODE 3
            v += u2f(bias[cg]);
            outf[(size_t)rg * ldc + cg] = v;
          }
        }
      }
    }
  }
}

__global__ void fill_kernel(float* __restrict__ p, const u16* __restrict__ val, int n) {
  int i = blockIdx.x * blockDim.x + threadIdx.x;
  if (i < n) p[i] = u2f(*val);
}

__global__ void adj_out_kernel(const float* __restrict__ r, void* __restrict__ out,
                               const int* __restrict__ flag) {
  int i = blockIdx.x * 256 + threadIdx.x;            // (b,v,w)
  int b = i >> 12, v = (i >> 6) & 63, w = i & 63;
  float val = r[(b << 12) + (w << 6) + v];           // pred_adj[b,v,w] = r[b,w,v]
  if (*flag) ((float*)out)[i] = val;
  else       ((u16*)out)[i] = f2u(val);
}

__global__ __launch_bounds__(512)
void msum_kernel(const float* __restrict__ r, const u16* __restrict__ M, u16* __restrict__ x) {
  const int bv = blockIdx.x;                          // b*64+v
  const int b = bv >> 6, v = bv & 63;
  __shared__ float s[64];
  if (threadIdx.x < 64) {
    const int w = threadIdx.x;
    s[w] = sigm(r[(b << 12) + (w << 6) + v]);
  }
  __syncthreads();
  const int m = threadIdx.x;                          // channel 0..511
  const u16* Mp = M + (((size_t)(b << 12) + (v << 6)) << 9) + m;
  float acc = 0.f;
#pragma unroll 8
  for (int w = 0; w < 64; w++) acc += s[w] * u2f(Mp[(size_t)w << 9]);
  x[(size_t)bv * 512 + m] = f2u(acc);
}

__global__ __launch_bounds__(256)
void gru_kernel(const float* __restrict__ gi, const float* __restrict__ gh,
                const u16* __restrict__ h, float* __restrict__ hn) {
  int i = blockIdx.x * 256 + threadIdx.x;             // 1024*512
  int row = i >> 9, d = i & 511;
  const float* gir = gi + (size_t)row * 1536;
  const float* ghr = gh + (size_t)row * 1536;
  float rr = sigm(gir[d] + ghr[d]);
  float z  = sigm(gir[512 + d] + ghr[512 + d]);
  float n  = tanhf(gir[1024 + d] + rr * ghr[1024 + d]);
  float hv = u2f(h[i]);
  hn[i] = (1.f - z) * n + z * hv;
}

__global__ __launch_bounds__(256)
void readout_kernel(const float* __restrict__ hn,
                    const u16* __restrict__ Wr1, const u16* __restrict__ br1,
                    const u16* __restrict__ Wr2, const u16* __restrict__ br2,
                    void* __restrict__ out, const int* __restrict__ flag) {
  const int row = blockIdx.x;
  const bool f32 = (*flag != 0);
  __shared__ float hrow[512];
  for (int d = threadIdx.x; d < 512; d += 256) hrow[d] = hn[(size_t)row * 512 + d];
  __syncthreads();
  const int wave = threadIdx.x >> 6, lane = threadIdx.x & 63;
  // 256 threads = 4 waves -> stride 4 (R3 bugfix: was 8, left columns unwritten)
  for (int j = wave; j < 28; j += 4) {
    const u16* wrow;
    float bias;
    size_t off;
    if (j < 26) { wrow = Wr1 + (size_t)j * 512; bias = u2f(br1[j]); off = 65536 + (size_t)row * 26 + j; }
    else { int jj = j - 26; wrow = Wr2 + (size_t)jj * 512; bias = u2f(br2[jj]); off = 92160 + (size_t)row * 2 + jj; }
    float s = 0.f;
    for (int d = lane; d < 512; d += 64) s += hrow[d] * u2f(wrow[d]);
#pragma unroll
    for (int o = 32; o; o >>= 1) s += __shfl_down(s, o);
    if (lane == 0) {
      float val = s + bias;
      if (f32) ((float*)out)[off] = val;
      else     ((u16*)out)[off] = f2u(val);
    }
  }
}

extern "C" void kernel_launch(void* const* d_in, const int* in_sizes, int n_in,
                              void* d_out, int out_size, void* d_ws, size_t ws_size,
                              hipStream_t stream)
{
  (void)in_sizes; (void)n_in; (void)out_size; (void)ws_size;
  const void* X = d_in[0];                // edge_features [16,64,64,512] (dtype detected)

  char* ws = (char*)d_ws;
  u16*   Mb    = (u16*)(ws);                    // 64 MB   message M, bf16 [65536,512]
  u16*   H1q   = (u16*)(ws + 67108864);         // 16 MB   link hidden, quarter [16384,512]
  float* pred1 = (float*)(ws + 83886080);       // 256 KB
  float* rbuf  = (float*)(ws + 84148224);       // 256 KB
  float* ubuf  = (float*)(ws + 84410368);       // 2 MB    u = nf@Wm_h^T + bm, fp32
  u16*   xb    = (u16*)(ws + 86507520);         // 1 MB    GRU input bf16 [1024,512]
  float* gi    = (float*)(ws + 87556096);       // 6 MB    [1024,1536]
  float* gh    = (float*)(ws + 93847552);       // 6 MB
  float* hn    = (float*)(ws + 100139008);      // 2 MB
  int*   flag  = (int*)  (ws + 102236160);      // dtype flag (1 = fp32 inputs)
  u16*   nfb   = (u16*)(ws + 102236416);        // bf16 copies of small tensors:
  u16*   Wmb   = (u16*)(ws + 103284992);
  u16*   bmb   = (u16*)(ws + 104333568);
  u16*   Wl1b  = (u16*)(ws + 104334592);
  u16*   bl1b  = (u16*)(ws + 104858880);
  u16*   Wl2b  = (u16*)(ws + 104859904);
  u16*   bl2b  = (u16*)(ws + 105384192);
  u16*   Wlob  = (u16*)(ws + 105385216);
  u16*   blob  = (u16*)(ws + 105386240);
  u16*   Wihb  = (u16*)(ws + 105387264);
  u16*   bihb  = (u16*)(ws + 106960128);
  u16*   Whhb  = (u16*)(ws + 106964224);
  u16*   bhhb  = (u16*)(ws + 108537088);
  u16*   Wr1b  = (u16*)(ws + 108541184);
  u16*   br1b  = (u16*)(ws + 108573952);
  u16*   Wr2b  = (u16*)(ws + 108574976);
  u16*   br2b  = (u16*)(ws + 108579072);
  // total ws use: ~108.6 MB

  detect_kernel<<<1, 256, 0, stream>>>((const float*)X, flag);

#define CVT(idx, dst, n) cvt_kernel<<<((n) + 255) / 256, 256, 0, stream>>>(d_in[idx], dst, n, flag)
  CVT(1,  nfb,  524288);
  CVT(4,  Wmb,  524288);
  CVT(5,  bmb,  512);
  CVT(6,  Wl1b, 262144);
  CVT(7,  bl1b, 512);
  CVT(8,  Wl2b, 262144);
  CVT(9,  bl2b, 512);
  CVT(10, Wlob, 512);
  CVT(11, blob, 1);
  CVT(12, Wihb, 786432);
  CVT(13, bihb, 1536);
  CVT(14, Whhb, 786432);
  CVT(15, bhhb, 1536);
  CVT(16, Wr1b, 13312);
  CVT(17, br1b, 26);
  CVT(18, Wr2b, 1024);
  CVT(19, br2b, 2);
#undef CVT

  // u = nf @ Wm[:, :512]^T + bm  (fp32)
  gemm_bt<3, false><<<dim3(4, 8), 256, 0, stream>>>(nfb, 512, 0, Wmb, 1024, 512, bmb,
      nullptr, nullptr, nullptr, nullptr, ubuf, 512, flag);
  // pred1 and rbuf (contiguous 131072 floats) = blo
  fill_kernel<<<512, 256, 0, stream>>>(pred1, blob, 131072);
  // M = relu(X @ Wm[:, 512:]^T + u)
  gemm_bt<0, true><<<dim3(4, 512), 256, 0, stream>>>(X, 512, 0, Wmb + 512, 1024, 512, nullptr,
      ubuf, nullptr, nullptr, Mb, nullptr, 512, flag);
  // round 1 link, quartered: H1q = relu(X_q @ Wl1^T + bl1); pred1_q += sum relu(H1q@Wl2^T+bl2)*Wlo
  for (int q = 0; q < 4; q++) {
    const size_t ro = (size_t)q * 16384;
    gemm_bt<1, true><<<dim3(4, 128), 256, 0, stream>>>(X, 512, ro, Wl1b, 512, 512, bl1b,
        nullptr, nullptr, nullptr, H1q, nullptr, 512, flag);
    gemm_bt<2, false><<<dim3(4, 128), 256, 0, stream>>>(H1q, 512, 0, Wl2b, 512, 512, bl2b,
        nullptr, Wlob, pred1 + ro, nullptr, nullptr, 512, flag);
  }
  // round 2 link on gated1 = sigmoid(pred1)*M, gating folded into epilogue (MODE 4)
  for (int q = 0; q < 4; q++) {
    const size_t ro = (size_t)q * 16384;
    gemm_bt<4, false><<<dim3(4, 128), 256, 0, stream>>>(Mb, 512, ro, Wl1b, 512, 512, bl1b,
        nullptr, nullptr, pred1 + ro, H1q, nullptr, 512, flag);
    gemm_bt<2, false><<<dim3(4, 128), 256, 0, stream>>>(H1q, 512, 0, Wl2b, 512, 512, bl2b,
        nullptr, Wlob, rbuf + ro, nullptr, nullptr, 512, flag);
  }
  // pred_adj[b,v,w] = rbuf[b,w,v]
  adj_out_kernel<<<256, 256, 0, stream>>>(rbuf, d_out, flag);
  // x[b,v,:] = sum_w sigmoid(rbuf[b,w,v]) * M[b,:,v,w]
  msum_kernel<<<1024, 512, 0, stream>>>(rbuf, Mb, xb);
  // GRU gates
  gemm_bt<3, false><<<dim3(12, 8), 256, 0, stream>>>(xb, 512, 0, Wihb, 512, 512, bihb,
      nullptr, nullptr, nullptr, nullptr, gi, 1536, flag);
  gemm_bt<3, false><<<dim3(12, 8), 256, 0, stream>>>(nfb, 512, 0, Whhb, 512, 512, bhhb,
      nullptr, nullptr, nullptr, nullptr, gh, 1536, flag);
  gru_kernel<<<2048, 256, 0, stream>>>(gi, gh, nfb, hn);
  readout_kernel<<<1024, 256, 0, stream>>>(hn, Wr1b, br1b, Wr2b, br2b, d_out, flag);
}

// Round 5
// 1336.051 us; speedup vs baseline: 1.0155x; 1.0155x over previous
//
#include <hip/hip_runtime.h>
#include <stdint.h>
#include <stddef.h>

using u16 = unsigned short;

__device__ __forceinline__ float u2f(u16 u) {
  union { unsigned i; float f; } c; c.i = ((unsigned)u) << 16; return c.f;
}
__device__ __forceinline__ u16 f2u(float f) {
  union { float f; unsigned i; } c; c.f = f;
  unsigned u = c.i;
  u += 0x7fffu + ((u >> 16) & 1u);   // RNE to bf16
  return (u16)(u >> 16);
}
__device__ __forceinline__ float sigm(float x) { return 1.f / (1.f + expf(-x)); }

typedef __attribute__((ext_vector_type(8))) short bfrag;   // 8 bf16 = 4 VGPRs
typedef __attribute__((ext_vector_type(4))) float f32x4;

// LDS row stride: 64 data u16 + 8 pad = 72 u16 (144 B = 9*16B, keeps b128 aligned).
// Unpadded (64 u16 = 128 B) put every fragment-read lane chunk on bank-quad 4*quad
// -> 4/32 banks active -> ~8x LDS serialization (R4: SQ_LDS_BANK_CONFLICT 1.26e7,
// MfmaUtil 5%). With 72: chunk bank = 4*((row+quad)%8) -> all 32 banks covered.
#define LDS_STRIDE 72

// ---- dtype detection: fp32 N(0,1) words land in [1e-6,1e4]; bf16 pairs
// reinterpreted as fp32 land at ~1e33..Inf or ~1e-38.
__global__ void detect_kernel(const float* __restrict__ x, int* __restrict__ flag) {
  __shared__ int cnt;
  if (threadIdx.x == 0) cnt = 0;
  __syncthreads();
  int local = 0;
  for (int i = threadIdx.x; i < 8192; i += 256) {
    float v = x[i];
    float a = fabsf(v);
    if (a > 1e-6f && a < 1e4f) local++;    // NaN/Inf/denorm/huge all fail
  }
  atomicAdd(&cnt, local);
  __syncthreads();
  if (threadIdx.x == 0) *flag = (cnt > 6144) ? 1 : 0;   // 1 = inputs are fp32
}

// convert (or copy) a tensor to bf16 in ws
__global__ void cvt_kernel(const void* __restrict__ src, u16* __restrict__ dst,
                           int n, const int* __restrict__ flag) {
  int i = blockIdx.x * 256 + threadIdx.x;
  if (i >= n) return;
  if (*flag) dst[i] = f2u(((const float*)src)[i]);
  else       dst[i] = ((const u16*)src)[i];
}

// C = epilogue(A @ W^T). A:[rows,K] (bf16, or runtime fp32 if ADYN), row-major lda.
// W:[cols,K] bf16 row-major ldw. rows%128==0, cols%128==0, K%64==0.
// MODE 0: outb = bf16(relu(acc + ubuf[(b*64+w)*512 + col]))   (ubuf holds bm already)
// MODE 1: outb = bf16(relu(acc + bias[col]))
// MODE 2: atomicAdd(pred[row], sum_col relu(acc + bias[col]) * wlo[col])
// MODE 3: outf = acc + bias[col]
// MODE 4: outb = bf16(relu(sigm(pred[row]) * acc + bias[col]))
template <int MODE, bool ADYN>
__global__ __launch_bounds__(256)
void gemm_bt(const void* __restrict__ Av, int lda, size_t abase,
             const u16* __restrict__ W, int ldw, int K,
             const u16* __restrict__ bias,
             const float* __restrict__ ubuf,
             const u16* __restrict__ wlo,
             float* __restrict__ pred,
             u16* __restrict__ outb,
             float* __restrict__ outf,
             int ldc,
             const int* __restrict__ aflag)
{
  __shared__ u16 As[128 * LDS_STRIDE];
  __shared__ u16 Bs[128 * LDS_STRIDE];
  const int tid  = threadIdx.x;
  const int wave = tid >> 6, lane = tid & 63;
  const int wr = wave >> 1, wc = wave & 1;
  const int quad = lane >> 4, l16 = lane & 15;
  const int row0 = blockIdx.y * 128;
  const int col0 = blockIdx.x * 128;
  bool a32 = false;
  if (ADYN) a32 = (*aflag != 0);

  f32x4 acc[4][4];
#pragma unroll
  for (int i = 0; i < 4; i++)
#pragma unroll
    for (int j = 0; j < 4; j++)
#pragma unroll
      for (int r = 0; r < 4; r++) acc[i][j][r] = 0.f;

  for (int k0 = 0; k0 < K; k0 += 64) {
    uint4 ra[4], rb[4];
#pragma unroll
    for (int i = 0; i < 4; i++) {
      const int idx  = i * 256 + tid;        // 1024 16B-chunks per tile
      const int srow = idx >> 3;             // 0..127
      const int scol = (idx & 7) * 8;        // 0..56, elems
      const size_t aoff = (abase + (size_t)(row0 + srow)) * lda + k0 + scol;
      if (ADYN && a32) {
        const float* p = (const float*)Av + aoff;
        float4 f0 = *(const float4*)(p);
        float4 f1 = *(const float4*)(p + 4);
        ra[i].x = (unsigned)f2u(f0.x) | ((unsigned)f2u(f0.y) << 16);
        ra[i].y = (unsigned)f2u(f0.z) | ((unsigned)f2u(f0.w) << 16);
        ra[i].z = (unsigned)f2u(f1.x) | ((unsigned)f2u(f1.y) << 16);
        ra[i].w = (unsigned)f2u(f1.z) | ((unsigned)f2u(f1.w) << 16);
      } else {
        ra[i] = *(const uint4*)((const u16*)Av + aoff);
      }
      rb[i] = *(const uint4*)(W + (size_t)(col0 + srow) * ldw + k0 + scol);
    }
    __syncthreads();                         // prior tile's LDS reads complete
#pragma unroll
    for (int i = 0; i < 4; i++) {
      const int idx  = i * 256 + tid;
      const int srow = idx >> 3;
      const int scol = (idx & 7) * 8;
      *(uint4*)(As + srow * LDS_STRIDE + scol) = ra[i];
      *(uint4*)(Bs + srow * LDS_STRIDE + scol) = rb[i];
    }
    __syncthreads();
#pragma unroll
    for (int kk = 0; kk < 64; kk += 32) {
      bfrag af[4], bfr[4];
#pragma unroll
      for (int mt = 0; mt < 4; mt++)
        af[mt] = *(const bfrag*)(As + (wr * 64 + mt * 16 + l16) * LDS_STRIDE + kk + quad * 8);
#pragma unroll
      for (int nt = 0; nt < 4; nt++)
        bfr[nt] = *(const bfrag*)(Bs + (wc * 64 + nt * 16 + l16) * LDS_STRIDE + kk + quad * 8);
#pragma unroll
      for (int mt = 0; mt < 4; mt++)
#pragma unroll
        for (int nt = 0; nt < 4; nt++)
          acc[mt][nt] = __builtin_amdgcn_mfma_f32_16x16x32_bf16(af[mt], bfr[nt], acc[mt][nt], 0, 0, 0);
    }
  }

  // C/D layout (verified m89/m91): col = lane&15, row = quad*4 + reg
#pragma unroll
  for (int mt = 0; mt < 4; mt++) {
    if (MODE == 2) {
#pragma unroll
      for (int r = 0; r < 4; r++) {
        const int rg = row0 + wr * 64 + mt * 16 + quad * 4 + r;
        float s = 0.f;
#pragma unroll
        for (int nt = 0; nt < 4; nt++) {
          const int cg = col0 + wc * 64 + nt * 16 + l16;
          float v = acc[mt][nt][r] + u2f(bias[cg]);
          v = fmaxf(v, 0.f);
          s += v * u2f(wlo[cg]);
        }
#pragma unroll
        for (int off = 1; off < 16; off <<= 1) s += __shfl_xor(s, off, 16);
        if (l16 == 0) atomicAdd(pred + rg, s);
      }
    } else {
#pragma unroll
      for (int nt = 0; nt < 4; nt++) {
#pragma unroll
        for (int r = 0; r < 4; r++) {
          const int rg = row0 + wr * 64 + mt * 16 + quad * 4 + r;
          const int cg = col0 + wc * 64 + nt * 16 + l16;
          float v = acc[mt][nt][r];
          if (MODE == 0) {
            const int urow = ((rg >> 12) << 6) | (rg & 63);   // b*64 + w
            v += ubuf[(size_t)urow * 512 + cg];
            v = fmaxf(v, 0.f);
            outb[(size_t)rg * ldc + cg] = f2u(v);
          } else if (MODE == 1) {
            v += u2f(bias[cg]);
            v = fmaxf(v, 0.f);
            outb[(size_t)rg * ldc + cg] = f2u(v);
          } else if (MODE == 4) {
            const float sg = sigm(pred[rg]);
            v = sg * v + u2f(bias[cg]);
            v = fmaxf(v, 0.f);
            outb[(size_t)rg * ldc + cg] = f2u(v);
          } else {  // MODE 3
            v += u2f(bias[cg]);
            outf[(size_t)rg * ldc + cg] = v;
          }
        }
      }
    }
  }
}

__global__ void fill_kernel(float* __restrict__ p, const u16* __restrict__ val, int n) {
  int i = blockIdx.x * blockDim.x + threadIdx.x;
  if (i < n) p[i] = u2f(*val);
}

__global__ void adj_out_kernel(const float* __restrict__ r, void* __restrict__ out,
                               const int* __restrict__ flag) {
  int i = blockIdx.x * 256 + threadIdx.x;            // (b,v,w)
  int b = i >> 12, v = (i >> 6) & 63, w = i & 63;
  float val = r[(b << 12) + (w << 6) + v];           // pred_adj[b,v,w] = r[b,w,v]
  if (*flag) ((float*)out)[i] = val;
  else       ((u16*)out)[i] = f2u(val);
}

__global__ __launch_bounds__(512)
void msum_kernel(const float* __restrict__ r, const u16* __restrict__ M, u16* __restrict__ x) {
  const int bv = blockIdx.x;                          // b*64+v
  const int b = bv >> 6, v = bv & 63;
  __shared__ float s[64];
  if (threadIdx.x < 64) {
    const int w = threadIdx.x;
    s[w] = sigm(r[(b << 12) + (w << 6) + v]);
  }
  __syncthreads();
  const int m = threadIdx.x;                          // channel 0..511
  const u16* Mp = M + (((size_t)(b << 12) + (v << 6)) << 9) + m;
  float acc = 0.f;
#pragma unroll 8
  for (int w = 0; w < 64; w++) acc += s[w] * u2f(Mp[(size_t)w << 9]);
  x[(size_t)bv * 512 + m] = f2u(acc);
}

__global__ __launch_bounds__(256)
void gru_kernel(const float* __restrict__ gi, const float* __restrict__ gh,
                const u16* __restrict__ h, float* __restrict__ hn) {
  int i = blockIdx.x * 256 + threadIdx.x;             // 1024*512
  int row = i >> 9, d = i & 511;
  const float* gir = gi + (size_t)row * 1536;
  const float* ghr = gh + (size_t)row * 1536;
  float rr = sigm(gir[d] + ghr[d]);
  float z  = sigm(gir[512 + d] + ghr[512 + d]);
  float n  = tanhf(gir[1024 + d] + rr * ghr[1024 + d]);
  float hv = u2f(h[i]);
  hn[i] = (1.f - z) * n + z * hv;
}

__global__ __launch_bounds__(256)
void readout_kernel(const float* __restrict__ hn,
                    const u16* __restrict__ Wr1, const u16* __restrict__ br1,
                    const u16* __restrict__ Wr2, const u16* __restrict__ br2,
                    void* __restrict__ out, const int* __restrict__ flag) {
  const int row = blockIdx.x;
  const bool f32 = (*flag != 0);
  __shared__ float hrow[512];
  for (int d = threadIdx.x; d < 512; d += 256) hrow[d] = hn[(size_t)row * 512 + d];
  __syncthreads();
  const int wave = threadIdx.x >> 6, lane = threadIdx.x & 63;
  // 256 threads = 4 waves -> stride 4 (R3 bugfix: was 8, left columns unwritten)
  for (int j = wave; j < 28; j += 4) {
    const u16* wrow;
    float bias;
    size_t off;
    if (j < 26) { wrow = Wr1 + (size_t)j * 512; bias = u2f(br1[j]); off = 65536 + (size_t)row * 26 + j; }
    else { int jj = j - 26; wrow = Wr2 + (size_t)jj * 512; bias = u2f(br2[jj]); off = 92160 + (size_t)row * 2 + jj; }
    float s = 0.f;
    for (int d = lane; d < 512; d += 64) s += hrow[d] * u2f(wrow[d]);
#pragma unroll
    for (int o = 32; o; o >>= 1) s += __shfl_down(s, o);
    if (lane == 0) {
      float val = s + bias;
      if (f32) ((float*)out)[off] = val;
      else     ((u16*)out)[off] = f2u(val);
    }
  }
}

extern "C" void kernel_launch(void* const* d_in, const int* in_sizes, int n_in,
                              void* d_out, int out_size, void* d_ws, size_t ws_size,
                              hipStream_t stream)
{
  (void)in_sizes; (void)n_in; (void)out_size; (void)ws_size;
  const void* X = d_in[0];                // edge_features [16,64,64,512] (dtype detected)

  char* ws = (char*)d_ws;
  u16*   Mb    = (u16*)(ws);                    // 64 MB   message M, bf16 [65536,512]
  u16*   H1q   = (u16*)(ws + 67108864);         // 16 MB   link hidden, quarter [16384,512]
  float* pred1 = (float*)(ws + 83886080);       // 256 KB
  float* rbuf  = (float*)(ws + 84148224);       // 256 KB
  float* ubuf  = (float*)(ws + 84410368);       // 2 MB    u = nf@Wm_h^T + bm, fp32
  u16*   xb    = (u16*)(ws + 86507520);         // 1 MB    GRU input bf16 [1024,512]
  float* gi    = (float*)(ws + 87556096);       // 6 MB    [1024,1536]
  float* gh    = (float*)(ws + 93847552);       // 6 MB
  float* hn    = (float*)(ws + 100139008);      // 2 MB
  int*   flag  = (int*)  (ws + 102236160);      // dtype flag (1 = fp32 inputs)
  u16*   nfb   = (u16*)(ws + 102236416);        // bf16 copies of small tensors:
  u16*   Wmb   = (u16*)(ws + 103284992);
  u16*   bmb   = (u16*)(ws + 104333568);
  u16*   Wl1b  = (u16*)(ws + 104334592);
  u16*   bl1b  = (u16*)(ws + 104858880);
  u16*   Wl2b  = (u16*)(ws + 104859904);
  u16*   bl2b  = (u16*)(ws + 105384192);
  u16*   Wlob  = (u16*)(ws + 105385216);
  u16*   blob  = (u16*)(ws + 105386240);
  u16*   Wihb  = (u16*)(ws + 105387264);
  u16*   bihb  = (u16*)(ws + 106960128);
  u16*   Whhb  = (u16*)(ws + 106964224);
  u16*   bhhb  = (u16*)(ws + 108537088);
  u16*   Wr1b  = (u16*)(ws + 108541184);
  u16*   br1b  = (u16*)(ws + 108573952);
  u16*   Wr2b  = (u16*)(ws + 108574976);
  u16*   br2b  = (u16*)(ws + 108579072);
  // total ws use: ~108.6 MB

  detect_kernel<<<1, 256, 0, stream>>>((const float*)X, flag);

#define CVT(idx, dst, n) cvt_kernel<<<((n) + 255) / 256, 256, 0, stream>>>(d_in[idx], dst, n, flag)
  CVT(1,  nfb,  524288);
  CVT(4,  Wmb,  524288);
  CVT(5,  bmb,  512);
  CVT(6,  Wl1b, 262144);
  CVT(7,  bl1b, 512);
  CVT(8,  Wl2b, 262144);
  CVT(9,  bl2b, 512);
  CVT(10, Wlob, 512);
  CVT(11, blob, 1);
  CVT(12, Wihb, 786432);
  CVT(13, bihb, 1536);
  CVT(14, Whhb, 786432);
  CVT(15, bhhb, 1536);
  CVT(16, Wr1b, 13312);
  CVT(17, br1b, 26);
  CVT(18, Wr2b, 1024);
  CVT(19, br2b, 2);
#undef CVT

  // u = nf @ Wm[:, :512]^T + bm  (fp32)
  gemm_bt<3, false><<<dim3(4, 8), 256, 0, stream>>>(nfb, 512, 0, Wmb, 1024, 512, bmb,
      nullptr, nullptr, nullptr, nullptr, ubuf, 512, flag);
  // pred1 and rbuf (contiguous 131072 floats) = blo
  fill_kernel<<<512, 256, 0, stream>>>(pred1, blob, 131072);
  // M = relu(X @ Wm[:, 512:]^T + u)
  gemm_bt<0, true><<<dim3(4, 512), 256, 0, stream>>>(X, 512, 0, Wmb + 512, 1024, 512, nullptr,
      ubuf, nullptr, nullptr, Mb, nullptr, 512, flag);
  // round 1 link, quartered: H1q = relu(X_q @ Wl1^T + bl1); pred1_q += sum relu(H1q@Wl2^T+bl2)*Wlo
  for (int q = 0; q < 4; q++) {
    const size_t ro = (size_t)q * 16384;
    gemm_bt<1, true><<<dim3(4, 128), 256, 0, stream>>>(X, 512, ro, Wl1b, 512, 512, bl1b,
        nullptr, nullptr, nullptr, H1q, nullptr, 512, flag);
    gemm_bt<2, false><<<dim3(4, 128), 256, 0, stream>>>(H1q, 512, 0, Wl2b, 512, 512, bl2b,
        nullptr, Wlob, pred1 + ro, nullptr, nullptr, 512, flag);
  }
  // round 2 link on gated1 = sigmoid(pred1)*M, gating folded into epilogue (MODE 4)
  for (int q = 0; q < 4; q++) {
    const size_t ro = (size_t)q * 16384;
    gemm_bt<4, false><<<dim3(4, 128), 256, 0, stream>>>(Mb, 512, ro, Wl1b, 512, 512, bl1b,
        nullptr, nullptr, pred1 + ro, H1q, nullptr, 512, flag);
    gemm_bt<2, false><<<dim3(4, 128), 256, 0, stream>>>(H1q, 512, 0, Wl2b, 512, 512, bl2b,
        nullptr, Wlob, rbuf + ro, nullptr, nullptr, 512, flag);
  }
  // pred_adj[b,v,w] = rbuf[b,w,v]
  adj_out_kernel<<<256, 256, 0, stream>>>(rbuf, d_out, flag);
  // x[b,v,:] = sum_w sigmoid(rbuf[b,w,v]) * M[b,:,v,w]
  msum_kernel<<<1024, 512, 0, stream>>>(rbuf, Mb, xb);
  // GRU gates
  gemm_bt<3, false><<<dim3(12, 8), 256, 0, stream>>>(xb, 512, 0, Wihb, 512, 512, bihb,
      nullptr, nullptr, nullptr, nullptr, gi, 1536, flag);
  gemm_bt<3, false><<<dim3(12, 8), 256, 0, stream>>>(nfb, 512, 0, Whhb, 512, 512, bhhb,
      nullptr, nullptr, nullptr, nullptr, gh, 1536, flag);
  gru_kernel<<<2048, 256, 0, stream>>>(gi, gh, nfb, hn);
  readout_kernel<<<1024, 256, 0, stream>>>(hn, Wr1b, br1b, Wr2b, br2b, d_out, flag);
}

// Round 6
// 1005.192 us; speedup vs baseline: 1.3498x; 1.3291x over previous
//
#include <hip/hip_runtime.h>
#include <stdint.h>
#include <stddef.h>

// Inputs/outputs are fp32 (proved R1/R2 NaN under bf16 interpretation vs R3/R4
// passing with the runtime-detect selecting the fp32 branch). Weights are
// converted once to bf16 in ws; GEMMs run bf16 MFMA with fp32 accumulate.

using u16 = unsigned short;
using u32 = unsigned int;

__device__ __forceinline__ float u2f(u16 u) {
  union { unsigned i; float f; } c; c.i = ((unsigned)u) << 16; return c.f;
}
__device__ __forceinline__ u16 f2u(float f) {
  union { float f; unsigned i; } c; c.f = f;
  unsigned u = c.i;
  u += 0x7fffu + ((u >> 16) & 1u);   // RNE to bf16
  return (u16)(u >> 16);
}
__device__ __forceinline__ u32 pk2(float lo, float hi) {
  return (u32)f2u(lo) | ((u32)f2u(hi) << 16);
}
__device__ __forceinline__ float sigm(float x) { return 1.f / (1.f + expf(-x)); }

typedef __attribute__((ext_vector_type(8))) short bfrag;   // 8 bf16 = 4 VGPRs
typedef __attribute__((ext_vector_type(4))) float f32x4;

__device__ __forceinline__ void gl_lds16(const u16* g, u16* l) {
  __builtin_amdgcn_global_load_lds((const __attribute__((address_space(1))) void*)g,
                                   (__attribute__((address_space(3))) void*)l,
                                   16, 0, 0);
}

// fp32 -> bf16 weight conversion
__global__ void cvt_kernel(const float* __restrict__ src, u16* __restrict__ dst, int n) {
  int i = blockIdx.x * 256 + threadIdx.x;
  if (i < n) dst[i] = f2u(src[i]);
}

// C = epilogue(A @ W^T). A:[rows,K] row-major lda (fp32 if A32 else bf16).
// W:[cols,K] bf16 row-major ldw. rows%128==0, cols%128==0, K%64==0.
// MODE 0: outb = bf16(relu(acc + ubuf[(b*64+w)*512 + col]))   (ubuf holds bm)
// MODE 1: outb = bf16(relu(acc + bias[col]))
// MODE 2: atomicAdd(pred[row], sum_col relu(acc + bias[col]) * wlo[col])
// MODE 3: outf = acc + bias[col]      (fp32 out, direct stores)
// MODE 4: outb = bf16(relu(sigm(pred[row]) * acc + bias[col]))
// MODE 5: fused: blockIdx.x<4 -> MODE0-style into outb; else W2/ldw2, MODE1-style into outb2
template <int MODE, bool A32>
__global__ __launch_bounds__(256)
void gemm_bt(const void* __restrict__ Av, int lda, size_t abase,
             const u16* __restrict__ W, int ldw, int K,
             const u16* __restrict__ bias,
             const float* __restrict__ ubuf,
             const u16* __restrict__ wlo,
             float* __restrict__ pred,
             u16* __restrict__ outb,
             float* __restrict__ outf,
             int ldc,
             const u16* __restrict__ W2, int ldw2, u16* __restrict__ outb2)
{
  // LDS: A32: As 128x72 (padded, VGPR-staged) + Bs 128x64 = 17408 u16 = 34816 B
  //      !A32: As 128x64 + Bs 128x64 (both global_load_lds)   = 16384 u16
  // epilogue reuses smem as a 128x136 bf16 tile (17408 u16) for coalesced C writes
  __shared__ u16 smem[17408];
  constexpr int ASTR = A32 ? 72 : 64;
  u16* As = smem;
  u16* Bs = smem + (A32 ? 9216 : 8192);

  const int tid  = threadIdx.x;
  const int wave = tid >> 6, lane = tid & 63;
  const int wr = wave >> 1, wc = wave & 1;
  const int quad = lane >> 4, l16 = lane & 15;
  const int srow8 = lane >> 3;          // row within an 8-row staging chunk
  const int scol8 = (lane & 7) * 8;     // col elems within row
  const int row0 = blockIdx.y * 128;
  const bool isM = (MODE != 5) || (blockIdx.x < 4);
  const int col0 = (MODE == 5 ? (blockIdx.x & 3) : blockIdx.x) * 128;
  const u16* Wp  = (MODE == 5 && !isM) ? W2  : W;
  const int ldwp = (MODE == 5 && !isM) ? ldw2 : ldw;

  f32x4 acc[4][4];
#pragma unroll
  for (int i = 0; i < 4; i++)
#pragma unroll
    for (int j = 0; j < 4; j++)
#pragma unroll
      for (int r = 0; r < 4; r++) acc[i][j][r] = 0.f;

  float4 rf[8];
  uint4  ra[4];
  if constexpr (A32) {
#pragma unroll
    for (int i = 0; i < 4; i++) {
      const int idx = i * 256 + tid, sr = idx >> 3, sc = (idx & 7) * 8;
      const float* p = (const float*)Av + (abase + (size_t)(row0 + sr)) * lda + sc;
      rf[2 * i] = *(const float4*)p;
      rf[2 * i + 1] = *(const float4*)(p + 4);
    }
#pragma unroll
    for (int i = 0; i < 4; i++) {
      ra[i].x = pk2(rf[2 * i].x, rf[2 * i].y);
      ra[i].y = pk2(rf[2 * i].z, rf[2 * i].w);
      ra[i].z = pk2(rf[2 * i + 1].x, rf[2 * i + 1].y);
      ra[i].w = pk2(rf[2 * i + 1].z, rf[2 * i + 1].w);
    }
  }

  for (int k0 = 0; k0 < K; k0 += 64) {
    __syncthreads();                     // prior tile's LDS consumers done
    if constexpr (A32) {
#pragma unroll
      for (int i = 0; i < 4; i++) {
        const int idx = i * 256 + tid, sr = idx >> 3, sc = (idx & 7) * 8;
        *(uint4*)(As + sr * ASTR + sc) = ra[i];
      }
    } else {
#pragma unroll
      for (int i = 0; i < 4; i++) {
        const int chunk = wave * 4 + i;
        gl_lds16((const u16*)Av + (abase + (size_t)(row0 + chunk * 8 + srow8)) * lda + k0 + scol8,
                 As + chunk * 512 + lane * 8);
      }
    }
#pragma unroll
    for (int i = 0; i < 4; i++) {
      const int chunk = wave * 4 + i;
      gl_lds16(Wp + (size_t)(col0 + chunk * 8 + srow8) * ldwp + k0 + scol8,
               Bs + chunk * 512 + lane * 8);
    }
    __syncthreads();                     // drains global_load_lds + ds_writes

    const bool more = (k0 + 64 < K);
    if constexpr (A32) {
      if (more) {                        // prefetch next A tile before compute
#pragma unroll
        for (int i = 0; i < 4; i++) {
          const int idx = i * 256 + tid, sr = idx >> 3, sc = (idx & 7) * 8;
          const float* p = (const float*)Av + (abase + (size_t)(row0 + sr)) * lda + (k0 + 64) + sc;
          rf[2 * i] = *(const float4*)p;
          rf[2 * i + 1] = *(const float4*)(p + 4);
        }
      }
    }

#pragma unroll
    for (int kk = 0; kk < 64; kk += 32) {
      bfrag af[4], bf[4];
#pragma unroll
      for (int mt = 0; mt < 4; mt++)
        af[mt] = *(const bfrag*)(As + (wr * 64 + mt * 16 + l16) * ASTR + kk + quad * 8);
#pragma unroll
      for (int nt = 0; nt < 4; nt++)
        bf[nt] = *(const bfrag*)(Bs + (wc * 64 + nt * 16 + l16) * 64 + kk + quad * 8);
#pragma unroll
      for (int mt = 0; mt < 4; mt++)
#pragma unroll
        for (int nt = 0; nt < 4; nt++)
          acc[mt][nt] = __builtin_amdgcn_mfma_f32_16x16x32_bf16(af[mt], bf[nt], acc[mt][nt], 0, 0, 0);
    }

    if constexpr (A32) {
      if (more) {                        // vmcnt wait lands here, after MFMAs
#pragma unroll
        for (int i = 0; i < 4; i++) {
          ra[i].x = pk2(rf[2 * i].x, rf[2 * i].y);
          ra[i].y = pk2(rf[2 * i].z, rf[2 * i].w);
          ra[i].z = pk2(rf[2 * i + 1].x, rf[2 * i + 1].y);
          ra[i].w = pk2(rf[2 * i + 1].z, rf[2 * i + 1].w);
        }
      }
    }
  }

  // C/D layout (verified m89/m91): col = lane&15, row = quad*4 + reg
  if constexpr (MODE == 2) {
#pragma unroll
    for (int mt = 0; mt < 4; mt++) {
#pragma unroll
      for (int r = 0; r < 4; r++) {
        const int rg = row0 + wr * 64 + mt * 16 + quad * 4 + r;
        float s = 0.f;
#pragma unroll
        for (int nt = 0; nt < 4; nt++) {
          const int cg = col0 + wc * 64 + nt * 16 + l16;
          float v = acc[mt][nt][r] + u2f(bias[cg]);
          v = fmaxf(v, 0.f);
          s += v * u2f(wlo[cg]);
        }
#pragma unroll
        for (int off = 1; off < 16; off <<= 1) s += __shfl_xor(s, off, 16);
        if (l16 == 0) atomicAdd(pred + rg, s);
      }
    }
  } else if constexpr (MODE == 3) {
#pragma unroll
    for (int mt = 0; mt < 4; mt++)
#pragma unroll
      for (int nt = 0; nt < 4; nt++)
#pragma unroll
        for (int r = 0; r < 4; r++) {
          const int rg = row0 + wr * 64 + mt * 16 + quad * 4 + r;
          const int cg = col0 + wc * 64 + nt * 16 + l16;
          outf[(size_t)rg * ldc + cg] = acc[mt][nt][r] + u2f(bias[cg]);
        }
  } else {
    // bf16-matrix epilogue through LDS for coalesced 16B stores
    u16* tile = smem;                    // 128 x 136
    u16* outp = (MODE == 5 && !isM) ? outb2 : outb;
    __syncthreads();                     // all waves done with As/Bs
#pragma unroll
    for (int mt = 0; mt < 4; mt++)
#pragma unroll
      for (int nt = 0; nt < 4; nt++)
#pragma unroll
        for (int r = 0; r < 4; r++) {
          const int lrow = wr * 64 + mt * 16 + quad * 4 + r;
          const int lcol = wc * 64 + nt * 16 + l16;
          const int rg = row0 + lrow;
          const int cg = col0 + lcol;
          float v = acc[mt][nt][r];
          if (MODE == 0 || (MODE == 5 && isM)) {
            const size_t grow = abase + rg;
            const int urow = (int)(((grow >> 12) << 6) | (grow & 63));   // b*64 + w
            v += ubuf[(size_t)urow * 512 + cg];
            v = fmaxf(v, 0.f);
          } else if (MODE == 1 || MODE == 5) {
            v += u2f(bias[cg]);
            v = fmaxf(v, 0.f);
          } else {  // MODE 4
            v = sigm(pred[rg]) * v + u2f(bias[cg]);
            v = fmaxf(v, 0.f);
          }
          tile[lrow * 136 + lcol] = f2u(v);
        }
    __syncthreads();
    const int row = tid >> 1, half = tid & 1;
    const u16* src = tile + row * 136 + half * 64;
    u16* dst = outp + (size_t)(row0 + row) * ldc + col0 + half * 64;
#pragma unroll
    for (int j = 0; j < 8; j++)
      *(uint4*)(dst + j * 8) = *(const uint4*)(src + j * 8);
  }
}

__global__ void fill_kernel(float* __restrict__ p, const u16* __restrict__ val, int n) {
  int i = blockIdx.x * blockDim.x + threadIdx.x;
  if (i < n) p[i] = u2f(*val);
}

__global__ void adj_out_kernel(const float* __restrict__ r, float* __restrict__ out) {
  int i = blockIdx.x * 256 + threadIdx.x;            // (b,v,w)
  int b = i >> 12, v = (i >> 6) & 63, w = i & 63;
  out[i] = r[(b << 12) + (w << 6) + v];              // pred_adj[b,v,w] = r[b,w,v]
}

__global__ __launch_bounds__(512)
void msum_kernel(const float* __restrict__ r, const u16* __restrict__ M, u16* __restrict__ x) {
  const int bv = blockIdx.x;                          // b*64+v
  const int b = bv >> 6, v = bv & 63;
  __shared__ float s[64];
  if (threadIdx.x < 64) {
    const int w = threadIdx.x;
    s[w] = sigm(r[(b << 12) + (w << 6) + v]);
  }
  __syncthreads();
  const int m = threadIdx.x;                          // channel 0..511
  const u16* Mp = M + (((size_t)(b << 12) + (v << 6)) << 9) + m;
  float acc = 0.f;
#pragma unroll 8
  for (int w = 0; w < 64; w++) acc += s[w] * u2f(Mp[(size_t)w << 9]);
  x[(size_t)bv * 512 + m] = f2u(acc);
}

__global__ __launch_bounds__(256)
void gru_kernel(const float* __restrict__ gi, const float* __restrict__ gh,
                const u16* __restrict__ h, float* __restrict__ hn) {
  int i = blockIdx.x * 256 + threadIdx.x;             // 1024*512
  int row = i >> 9, d = i & 511;
  const float* gir = gi + (size_t)row * 1536;
  const float* ghr = gh + (size_t)row * 1536;
  float rr = sigm(gir[d] + ghr[d]);
  float z  = sigm(gir[512 + d] + ghr[512 + d]);
  float n  = tanhf(gir[1024 + d] + rr * ghr[1024 + d]);
  float hv = u2f(h[i]);
  hn[i] = (1.f - z) * n + z * hv;
}

__global__ __launch_bounds__(256)
void readout_kernel(const float* __restrict__ hn,
                    const u16* __restrict__ Wr1, const u16* __restrict__ br1,
                    const u16* __restrict__ Wr2, const u16* __restrict__ br2,
                    float* __restrict__ out) {
  const int row = blockIdx.x;
  __shared__ float hrow[512];
  for (int d = threadIdx.x; d < 512; d += 256) hrow[d] = hn[(size_t)row * 512 + d];
  __syncthreads();
  const int wave = threadIdx.x >> 6, lane = threadIdx.x & 63;
  for (int j = wave; j < 28; j += 4) {
    const u16* wrow;
    float bias;
    size_t off;
    if (j < 26) { wrow = Wr1 + (size_t)j * 512; bias = u2f(br1[j]); off = 65536 + (size_t)row * 26 + j; }
    else { int jj = j - 26; wrow = Wr2 + (size_t)jj * 512; bias = u2f(br2[jj]); off = 92160 + (size_t)row * 2 + jj; }
    float s = 0.f;
    for (int d = lane; d < 512; d += 64) s += hrow[d] * u2f(wrow[d]);
#pragma unroll
    for (int o = 32; o; o >>= 1) s += __shfl_down(s, o);
    if (lane == 0) out[off] = s + bias;
  }
}

extern "C" void kernel_launch(void* const* d_in, const int* in_sizes, int n_in,
                              void* d_out, int out_size, void* d_ws, size_t ws_size,
                              hipStream_t stream)
{
  (void)in_sizes; (void)n_in; (void)out_size;
  const void*  X  = d_in[0];                 // edge_features [16,64,64,512] fp32
  char* ws = (char*)d_ws;

  const bool big = (ws_size >= 158905344ULL);   // full-H1 fused path needs ~151.5 MiB

  // ---- workspace layouts ----
  u16 *Mb, *H1, *xb, *nfb, *Wmb, *bmb, *Wl1b, *bl1b, *Wl2b, *bl2b, *Wlob, *blob;
  u16 *Wihb, *bihb, *Whhb, *bhhb, *Wr1b, *br1b, *Wr2b, *br2b;
  float *pred1, *rbuf, *ubuf, *gi, *gh, *hn;
  if (big) {
    Mb    = (u16*)(ws);                         // 64 MB  M bf16 [65536,512]
    H1    = (u16*)(ws + 67108864);              // 64 MB  link hidden, full
    pred1 = (float*)(ws + 134217728);           // 256 KB
    rbuf  = (float*)(ws + 134479872);           // 256 KB
    ubuf  = (float*)(ws + 134742016);           // 2 MB
    xb    = (u16*)(ws + 136839168);             // 1 MB
    gi    = (float*)(ws + 137887744);           // 6 MB
    gh    = (float*)(ws + 144179200);           // 6 MB
    hn    = (float*)(ws + 150470656);           // 2 MB
    nfb   = (u16*)(ws + 152567808);
    Wmb   = (u16*)(ws + 153616384);
    bmb   = (u16*)(ws + 154664960);
    Wl1b  = (u16*)(ws + 154665984);
    bl1b  = (u16*)(ws + 155190272);
    Wl2b  = (u16*)(ws + 155191296);
    bl2b  = (u16*)(ws + 155715584);
    Wlob  = (u16*)(ws + 155716608);
    blob  = (u16*)(ws + 155717632);
    Wihb  = (u16*)(ws + 155718656);
    bihb  = (u16*)(ws + 157291520);
    Whhb  = (u16*)(ws + 157295616);
    bhhb  = (u16*)(ws + 158868480);
    Wr1b  = (u16*)(ws + 158872576);
    br1b  = (u16*)(ws + 158901248);
    Wr2b  = (u16*)(ws + 158902272);
    br2b  = (u16*)(ws + 158904320);
  } else {                                      // R4 known-good quartered layout
    Mb    = (u16*)(ws);
    H1    = (u16*)(ws + 67108864);              // 16 MB quarter here
    pred1 = (float*)(ws + 83886080);
    rbuf  = (float*)(ws + 84148224);
    ubuf  = (float*)(ws + 84410368);
    xb    = (u16*)(ws + 86507520);
    gi    = (float*)(ws + 87556096);
    gh    = (float*)(ws + 93847552);
    hn    = (float*)(ws + 100139008);
    nfb   = (u16*)(ws + 102236416);
    Wmb   = (u16*)(ws + 103284992);
    bmb   = (u16*)(ws + 104333568);
    Wl1b  = (u16*)(ws + 104334592);
    bl1b  = (u16*)(ws + 104858880);
    Wl2b  = (u16*)(ws + 104859904);
    bl2b  = (u16*)(ws + 105384192);
    Wlob  = (u16*)(ws + 105385216);
    blob  = (u16*)(ws + 105386240);
    Wihb  = (u16*)(ws + 105387264);
    bihb  = (u16*)(ws + 106960128);
    Whhb  = (u16*)(ws + 106964224);
    bhhb  = (u16*)(ws + 108537088);
    Wr1b  = (u16*)(ws + 108541184);
    br1b  = (u16*)(ws + 108573952);
    Wr2b  = (u16*)(ws + 108574976);
    br2b  = (u16*)(ws + 108579072);
  }

  float* out = (float*)d_out;

#define CVT(idx, dst, n) cvt_kernel<<<((n) + 255) / 256, 256, 0, stream>>>((const float*)d_in[idx], dst, n)
  CVT(1,  nfb,  524288);
  CVT(4,  Wmb,  524288);
  CVT(5,  bmb,  512);
  CVT(6,  Wl1b, 262144);
  CVT(7,  bl1b, 512);
  CVT(8,  Wl2b, 262144);
  CVT(9,  bl2b, 512);
  CVT(10, Wlob, 512);
  CVT(11, blob, 1);
  CVT(12, Wihb, 786432);
  CVT(13, bihb, 1536);
  CVT(14, Whhb, 786432);
  CVT(15, bhhb, 1536);
  CVT(16, Wr1b, 13312);
  CVT(17, br1b, 26);
  CVT(18, Wr2b, 1024);
  CVT(19, br2b, 2);
#undef CVT

  // u = nf @ Wm[:, :512]^T + bm  (fp32)
  gemm_bt<3, false><<<dim3(4, 8), 256, 0, stream>>>(nfb, 512, 0, Wmb, 1024, 512, bmb,
      nullptr, nullptr, nullptr, nullptr, ubuf, 512, nullptr, 0, nullptr);
  // pred1 & rbuf (contiguous 131072 floats) = blo
  fill_kernel<<<512, 256, 0, stream>>>(pred1, blob, 131072);

  if (big) {
    // fused: [Mb | H1] = relu(X @ [Wm_e | Wl1]^T + [u | bl1]), X read once
    gemm_bt<5, true><<<dim3(8, 512), 256, 0, stream>>>(X, 512, 0, Wmb + 512, 1024, 512,
        bl1b, ubuf, nullptr, nullptr, Mb, nullptr, 512, Wl1b, 512, H1);
    // pred1 += sum relu(H1 @ Wl2^T + bl2) * Wlo
    gemm_bt<2, false><<<dim3(4, 512), 256, 0, stream>>>(H1, 512, 0, Wl2b, 512, 512, bl2b,
        nullptr, Wlob, pred1, nullptr, nullptr, 512, nullptr, 0, nullptr);
    // H1 = relu(sigm(pred1)*(X@Wm-relu...)  -> gated link layer 1 on M
    gemm_bt<4, false><<<dim3(4, 512), 256, 0, stream>>>(Mb, 512, 0, Wl1b, 512, 512, bl1b,
        nullptr, nullptr, pred1, H1, nullptr, 512, nullptr, 0, nullptr);
    gemm_bt<2, false><<<dim3(4, 512), 256, 0, stream>>>(H1, 512, 0, Wl2b, 512, 512, bl2b,
        nullptr, Wlob, rbuf, nullptr, nullptr, 512, nullptr, 0, nullptr);
  } else {
    // M = relu(X @ Wm[:, 512:]^T + u)
    gemm_bt<0, true><<<dim3(4, 512), 256, 0, stream>>>(X, 512, 0, Wmb + 512, 1024, 512,
        nullptr, ubuf, nullptr, nullptr, Mb, nullptr, 512, nullptr, 0, nullptr);
    for (int q = 0; q < 4; q++) {
      const size_t ro = (size_t)q * 16384;
      gemm_bt<1, true><<<dim3(4, 128), 256, 0, stream>>>(X, 512, ro, Wl1b, 512, 512, bl1b,
          nullptr, nullptr, nullptr, H1, nullptr, 512, nullptr, 0, nullptr);
      gemm_bt<2, false><<<dim3(4, 128), 256, 0, stream>>>(H1, 512, 0, Wl2b, 512, 512, bl2b,
          nullptr, Wlob, pred1 + ro, nullptr, nullptr, 512, nullptr, 0, nullptr);
    }
    for (int q = 0; q < 4; q++) {
      const size_t ro = (size_t)q * 16384;
      gemm_bt<4, false><<<dim3(4, 128), 256, 0, stream>>>(Mb, 512, ro, Wl1b, 512, 512, bl1b,
          nullptr, nullptr, pred1 + ro, H1, nullptr, 512, nullptr, 0, nullptr);
      gemm_bt<2, false><<<dim3(4, 128), 256, 0, stream>>>(H1, 512, 0, Wl2b, 512, 512, bl2b,
          nullptr, Wlob, rbuf + ro, nullptr, nullptr, 512, nullptr, 0, nullptr);
    }
  }

  // pred_adj[b,v,w] = rbuf[b,w,v]
  adj_out_kernel<<<256, 256, 0, stream>>>(rbuf, out);
  // x[b,v,:] = sum_w sigmoid(rbuf[b,w,v]) * M[b,:,v,w]
  msum_kernel<<<1024, 512, 0, stream>>>(rbuf, Mb, xb);
  // GRU gates
  gemm_bt<3, false><<<dim3(12, 8), 256, 0, stream>>>(xb, 512, 0, Wihb, 512, 512, bihb,
      nullptr, nullptr, nullptr, nullptr, gi, 1536, nullptr, 0, nullptr);
  gemm_bt<3, false><<<dim3(12, 8), 256, 0, stream>>>(nfb, 512, 0, Whhb, 512, 512, bhhb,
      nullptr, nullptr, nullptr, nullptr, gh, 1536, nullptr, 0, nullptr);
  gru_kernel<<<2048, 256, 0, stream>>>(gi, gh, nfb, hn);
  readout_kernel<<<1024, 256, 0, stream>>>(hn, Wr1b, br1b, Wr2b, br2b, out);
}